// Round 8
// baseline (234.859 us; speedup 1.0000x reference)
//
#include <hip/hip_runtime.h>
#include <hip/hip_bf16.h>
#include <hip/hip_cooperative_groups.h>

namespace cg = cooperative_groups;

typedef __bf16 bf16x4 __attribute__((ext_vector_type(4)));
typedef __bf16 bf16x8 __attribute__((ext_vector_type(8)));
typedef float f32x4 __attribute__((ext_vector_type(4)));

#define N_PIX 4608      // 2*48*48
#define D_MODEL 512
#define QKV_N 1536
#define KSTR 72
#define GRID_BLKS 256   // 1 block/CU: always co-resident regardless of VGPR/LDS

// async global->LDS, 16B per lane. LDS dest is wave-uniform base; HW adds lane*16.
__device__ __forceinline__ void gload_lds16(const void* g, void* l) {
  __builtin_amdgcn_global_load_lds(
      (const __attribute__((address_space(1))) unsigned int*)g,
      (__attribute__((address_space(3))) unsigned int*)l, 16, 0, 0);
}

// ---- GEMM tile: C[BM x BN] = A[BM x K] * Bt[BN x K]^T, BK=32, dbuf, 4 waves ----
// Fragment layouts (verified m89): A[m=lane&15][k=quad*8+j]; Bt[n=lane&15][k=quad*8+j];
// C/D: row=quad*4+reg, col=lane&15.
template <int BM, int BN>
__device__ __forceinline__ void gemm_tile(
    const __bf16* __restrict__ A, const __bf16* __restrict__ Bt,
    void* __restrict__ C, int N, int K, int c_is_f32,
    int m0, int n0, __bf16* sA, __bf16* sB, int tid) {
  constexpr int MT = BM / 32, NT = BN / 32, AR = BM / 4, BR = BN / 4;
  int wv = tid >> 6, lane = tid & 63;
  int quad = lane >> 4, r16 = lane & 15;
  int rA = lane >> 2;           // 0..15
  int kc = (lane & 3) * 8;      // 0,8,16,24
  const __bf16* Ag0 = A + (long)(m0 + wv * AR + rA) * K + kc;
  const __bf16* Bg0 = Bt + (long)(n0 + wv * BR + rA) * K + kc;
  int mw = (wv & 1) * (BM / 2), nw = (wv >> 1) * (BN / 2);

  f32x4 acc[MT][NT];
#pragma unroll
  for (int mt = 0; mt < MT; ++mt)
#pragma unroll
    for (int nt = 0; nt < NT; ++nt) acc[mt][nt] = f32x4{0.f, 0.f, 0.f, 0.f};

  auto stage = [&](int buf, int k0) {
    gload_lds16(Ag0 + k0, &sA[buf * BM * 32 + (wv * AR) * 32]);
    if (AR == 32)
      gload_lds16(Ag0 + (long)16 * K + k0, &sA[buf * BM * 32 + (wv * AR + 16) * 32]);
    gload_lds16(Bg0 + k0, &sB[buf * BN * 32 + (wv * BR) * 32]);
    if (BR == 32)
      gload_lds16(Bg0 + (long)16 * K + k0, &sB[buf * BN * 32 + (wv * BR + 16) * 32]);
  };

  stage(0, 0);
  int cur = 0;
  for (int k0 = 0; k0 < K; k0 += 32) {
    __syncthreads();
    if (k0 + 32 < K) stage(cur ^ 1, k0 + 32);
    bf16x8 af[MT], bfr[NT];
#pragma unroll
    for (int mt = 0; mt < MT; ++mt)
      af[mt] = *(const bf16x8*)&sA[cur * BM * 32 + (mw + mt * 16 + r16) * 32 + quad * 8];
#pragma unroll
    for (int nt = 0; nt < NT; ++nt)
      bfr[nt] = *(const bf16x8*)&sB[cur * BN * 32 + (nw + nt * 16 + r16) * 32 + quad * 8];
#pragma unroll
    for (int mt = 0; mt < MT; ++mt)
#pragma unroll
      for (int nt = 0; nt < NT; ++nt)
        acc[mt][nt] = __builtin_amdgcn_mfma_f32_16x16x32_bf16(af[mt], bfr[nt], acc[mt][nt], 0, 0, 0);
    cur ^= 1;
  }

  __bf16* Cb = (__bf16*)C;
  float* Cf = (float*)C;
#pragma unroll
  for (int mt = 0; mt < MT; ++mt)
#pragma unroll
    for (int r = 0; r < 4; ++r) {
      int row = m0 + mw + mt * 16 + quad * 4 + r;
#pragma unroll
      for (int nt = 0; nt < NT; ++nt) {
        int col = n0 + nw + nt * 16 + r16;
        float v = acc[mt][nt][r];
        if (c_is_f32) Cf[(long)row * N + col] = v;
        else          Cb[(long)row * N + col] = (__bf16)v;
      }
    }
}

// ---- attention tile body (shared by coop + standalone), 256 threads ----
__device__ __forceinline__ void attn_tile(
    const __bf16* __restrict__ qkvb, __bf16* __restrict__ obf,
    int it, int tid, __bf16* sK, __bf16* sV) {
  int nB = it / 288;
  int rem = it - nB * 288;
  int head = rem / 36;
  int tile = rem - head * 36;
  int tr = tile / 6, tc = tile - tr * 6;
  int r0 = tr * 8, c0 = tc * 8;
  int loH = r0 - 3; loH = loH < 0 ? 0 : (loH > 41 ? 41 : loH);
  int loW = c0 - 3; loW = loW < 0 ? 0 : (loW > 41 ? 41 : loW);

  for (int j = tid; j < 196 * 8; j += 256) {
    int rowi = j >> 3, ch = j & 7;
    int rr = rowi / 14, cc = rowi - rr * 14;
    int hh = loH + rr; hh = hh > 47 ? 47 : hh;
    int wp = loW + cc; wp = wp > 47 ? 47 : wp;
    long base = (long)(nB * 2304 + hh * 48 + wp) * QKV_N + head * 64 + ch * 8;
    *(uint4*)&sK[rowi * KSTR + ch * 8] = *(const uint4*)&qkvb[base + 512];
    *(uint4*)&sV[rowi * KSTR + ch * 8] = *(const uint4*)&qkvb[base + 1024];
  }
  __syncthreads();

  int q = tid >> 2, s = tid & 3;      // 64 queries x 4 slices of 16 ch
  int qr = q >> 3, qc = q & 7;
  int h = r0 + qr, w = c0 + qc;
  int pix = nB * 2304 + h * 48 + w;
  int hs = h - 3; hs = hs < 0 ? 0 : (hs > 41 ? 41 : hs); hs -= loH;
  int ws = w - 3; ws = ws < 0 ? 0 : (ws > 41 ? 41 : ws); ws -= loW;
  int base = (hs * 14 + ws) * KSTR + s * 16;

  const bf16x8* qp = (const bf16x8*)&qkvb[(long)pix * QKV_N + head * 64 + s * 16];
  bf16x8 q0 = qp[0], q1 = qp[1];
  float qf[16];
#pragma unroll
  for (int t = 0; t < 8; ++t) {
    qf[t] = (float)q0[t];
    qf[8 + t] = (float)q1[t];
  }

  float lg[49];
#pragma unroll
  for (int j = 0; j < 49; ++j) {
    int a = j / 7, b = j % 7;
    const bf16x8* kp = (const bf16x8*)&sK[base + (a * 14 + b) * KSTR];
    bf16x8 k0 = kp[0], k1 = kp[1];
    float acc = 0.f;
#pragma unroll
    for (int t = 0; t < 8; ++t) {
      acc = fmaf(qf[t], (float)k0[t], acc);
      acc = fmaf(qf[8 + t], (float)k1[t], acc);
    }
    acc += __shfl_xor(acc, 1);
    acc += __shfl_xor(acc, 2);
    lg[j] = acc;
  }

  float mx = lg[0];
#pragma unroll
  for (int j = 1; j < 49; ++j) mx = fmaxf(mx, lg[j]);
  float sm = 0.f;
#pragma unroll
  for (int j = 0; j < 49; ++j) { lg[j] = __expf(lg[j] - mx); sm += lg[j]; }
  float inv = 1.f / sm;

  float ov[16];
#pragma unroll
  for (int t = 0; t < 16; ++t) ov[t] = 0.f;
#pragma unroll
  for (int j = 0; j < 49; ++j) {
    int a = j / 7, b = j % 7;
    float pj = lg[j] * inv;
    const bf16x8* vp = (const bf16x8*)&sV[base + (a * 14 + b) * KSTR];
    bf16x8 v0 = vp[0], v1 = vp[1];
#pragma unroll
    for (int t = 0; t < 8; ++t) {
      ov[t] = fmaf(pj, (float)v0[t], ov[t]);
      ov[8 + t] = fmaf(pj, (float)v1[t], ov[8 + t]);
    }
  }

  bf16x8 o0, o1;
#pragma unroll
  for (int t = 0; t < 8; ++t) {
    o0[t] = (__bf16)ov[t];
    o1[t] = (__bf16)ov[8 + t];
  }
  bf16x8* op = (bf16x8*)&obf[(long)pix * D_MODEL + head * 64 + s * 16];
  op[0] = o0;
  op[1] = o1;
}

// ---- prep item body (shared by coop + standalone) ----
__device__ __forceinline__ void prep_item(
    const float* __restrict__ x, const float* __restrict__ wq,
    const float* __restrict__ wo, __bf16* __restrict__ xbf,
    __bf16* __restrict__ wqT, __bf16* __restrict__ woT,
    int b, int tid, float(*ptile)[33]) {
  if (b < 2304) {
    int i = b * 1024 + tid * 4;
    float4 v = *(const float4*)&x[i];
    bf16x4 o = {(__bf16)v.x, (__bf16)v.y, (__bf16)v.z, (__bf16)v.w};
    *(bf16x4*)&xbf[i] = o;
    return;
  }
  const float* src; __bf16* dst; int C, bx, by;
  bool is_wq;
  if (b < 3072) {
    int t = b - 2304; src = wq; dst = wqT; C = 1536;
    bx = (t % 48) * 32; by = (t / 48) * 32; is_wq = true;
  } else {
    int t = b - 3072; src = wo; dst = woT; C = 512;
    bx = (t & 15) * 32; by = (t >> 4) * 32; is_wq = false;
  }
  int tx = tid & 31, ty = tid >> 5;
  __syncthreads();
#pragma unroll
  for (int i = 0; i < 32; i += 8)
    ptile[ty + i][tx] = src[(by + ty + i) * C + bx + tx];
  __syncthreads();
#pragma unroll
  for (int i = 0; i < 32; i += 8) {
    int outrow = bx + ty + i;
    float v = ptile[tx][ty + i];
    if (is_wq && outrow < 512) v *= 0.125f;  // fold q/sqrt(64)
    dst[outrow * 512 + by + tx] = (__bf16)v;
  }
}

// ---- single persistent cooperative kernel ----
__global__ __launch_bounds__(256) void natten_fused_kernel(
    const float* __restrict__ x, const float* __restrict__ wq,
    const float* __restrict__ wo, float* __restrict__ out,
    __bf16* __restrict__ xbf, __bf16* __restrict__ wqT,
    __bf16* __restrict__ woT, __bf16* __restrict__ qkvb,
    __bf16* __restrict__ obf) {
  cg::grid_group grid = cg::this_grid();
  __shared__ __align__(16) char shmem[2 * 196 * KSTR * sizeof(__bf16)];  // 56448 B
  __bf16* sK = (__bf16*)shmem;
  __bf16* sV = (__bf16*)(shmem + 196 * KSTR * sizeof(__bf16));
  __bf16* sA = (__bf16*)shmem;              // gemm: 2*128*32*2 = 16384 B
  __bf16* sB = (__bf16*)(shmem + 16384);
  float(*ptile)[33] = (float(*)[33])shmem;

  int bid = blockIdx.x, tid = threadIdx.x;

  // phase A: 3328 prep items (13 per block exactly)
  for (int b = bid; b < 3328; b += GRID_BLKS)
    prep_item(x, wq, wo, xbf, wqT, woT, b, tid, ptile);
  grid.sync();

  // phase B: QKV GEMM, 432 tiles of 128x128
  for (int t = bid; t < 432; t += GRID_BLKS) {
    __syncthreads();
    gemm_tile<128, 128>(xbf, wqT, qkvb, QKV_N, D_MODEL, 0,
                        (t / 12) * 128, (t % 12) * 128, sA, sB, tid);
  }
  grid.sync();

  // phase C: attention, 576 items
  for (int it = bid; it < 576; it += GRID_BLKS) {
    __syncthreads();
    attn_tile(qkvb, obf, it, tid, sK, sV);
  }
  grid.sync();

  // phase D: out GEMM, 288 tiles of 128x64
  for (int t = bid; t < 288; t += GRID_BLKS) {
    __syncthreads();
    gemm_tile<128, 64>(obf, woT, out, D_MODEL, D_MODEL, 1,
                       (t / 8) * 128, (t % 8) * 64, sA, sB, tid);
  }
}

// ---- standalone fallback kernels ----
__global__ __launch_bounds__(256) void prep_kernel(
    const float* __restrict__ x, const float* __restrict__ wq,
    const float* __restrict__ wo, __bf16* __restrict__ xbf,
    __bf16* __restrict__ wqT, __bf16* __restrict__ woT) {
  __shared__ float ptile[32][33];
  prep_item(x, wq, wo, xbf, wqT, woT, blockIdx.x, threadIdx.x, ptile);
}

template <int BM, int BN>
__global__ __launch_bounds__(256) void gemm_kernel(
    const __bf16* __restrict__ A, const __bf16* __restrict__ Bt,
    void* __restrict__ C, int N, int K, int c_is_f32) {
  __shared__ __bf16 sA[2 * BM * 32];
  __shared__ __bf16 sB[2 * BN * 32];
  gemm_tile<BM, BN>(A, Bt, C, N, K, c_is_f32,
                    blockIdx.y * BM, blockIdx.x * BN, sA, sB, threadIdx.x);
}

__global__ __launch_bounds__(256) void natten_attn_kernel(
    const __bf16* __restrict__ qkvb, __bf16* __restrict__ obf) {
  __shared__ __bf16 sK[196 * KSTR];
  __shared__ __bf16 sV[196 * KSTR];
  attn_tile(qkvb, obf, blockIdx.x, threadIdx.x, sK, sV);
}

// ---------------- launch ----------------

extern "C" void kernel_launch(void* const* d_in, const int* in_sizes, int n_in,
                              void* d_out, int out_size, void* d_ws, size_t ws_size,
                              hipStream_t stream) {
  const float* x = (const float*)d_in[0];      // (2,48,48,512)
  const float* wq = (const float*)d_in[1];     // (512,1536)
  const float* wo = (const float*)d_in[2];     // (512,512)
  float* out = (float*)d_out;                  // (2,48,48,512)

  __bf16* ws = (__bf16*)d_ws;
  __bf16* xbf  = ws;                            // 4608*512
  __bf16* wqT  = xbf + N_PIX * D_MODEL;         // 1536*512
  __bf16* woT  = wqT + QKV_N * D_MODEL;         // 512*512
  __bf16* qkvb = woT + D_MODEL * D_MODEL;       // 4608*1536
  __bf16* obf  = qkvb + N_PIX * QKV_N;          // 4608*512

  void* args[] = {(void*)&x, (void*)&wq, (void*)&wo, (void*)&out,
                  (void*)&xbf, (void*)&wqT, (void*)&woT, (void*)&qkvb, (void*)&obf};
  hipError_t err = hipLaunchCooperativeKernel(
      (void*)natten_fused_kernel, dim3(GRID_BLKS), dim3(256), args, 0, stream);
  if (err != hipSuccess) {
    // fallback: separate launches (known-good round-5 structure)
    prep_kernel<<<3328, 256, 0, stream>>>(x, wq, wo, xbf, wqT, woT);
    gemm_kernel<128, 128><<<dim3(QKV_N / 128, N_PIX / 128), 256, 0, stream>>>(
        xbf, wqT, qkvb, QKV_N, D_MODEL, 0);
    natten_attn_kernel<<<576, 256, 0, stream>>>(qkvb, obf);
    gemm_kernel<128, 64><<<dim3(D_MODEL / 64, N_PIX / 128), 256, 0, stream>>>(
        obf, woT, out, D_MODEL, D_MODEL, 1);
  }
}

// Round 9
// 123.792 us; speedup vs baseline: 1.8972x; 1.8972x over previous
//
#include <hip/hip_runtime.h>
#include <hip/hip_bf16.h>

typedef __bf16 bf16x4 __attribute__((ext_vector_type(4)));
typedef __bf16 bf16x8 __attribute__((ext_vector_type(8)));
typedef float f32x4 __attribute__((ext_vector_type(4)));

#define N_PIX 4608      // 2*48*48
#define D_MODEL 512
#define QKV_N 1536
#define KSTR 72

// async global->LDS, 16B per lane. LDS dest is wave-uniform base; HW adds lane*16.
__device__ __forceinline__ void gload_lds16(const void* g, void* l) {
  __builtin_amdgcn_global_load_lds(
      (const __attribute__((address_space(1))) unsigned int*)g,
      (__attribute__((address_space(3))) unsigned int*)l, 16, 0, 0);
}

// ---------------- fused prep: x->bf16 + both weight transposes ----------------
// blocks [0,2304): x convert; [2304,3072): w_qkv^T (q-scale folded); [3072,3328): w_out^T
__global__ __launch_bounds__(256) void prep_kernel(
    const float* __restrict__ x, const float* __restrict__ wq,
    const float* __restrict__ wo, __bf16* __restrict__ xbf,
    __bf16* __restrict__ wqT, __bf16* __restrict__ woT) {
  int b = blockIdx.x, tid = threadIdx.x;
  if (b < 2304) {
    int i = b * 1024 + tid * 4;
    float4 v = *(const float4*)&x[i];
    bf16x4 o = {(__bf16)v.x, (__bf16)v.y, (__bf16)v.z, (__bf16)v.w};
    *(bf16x4*)&xbf[i] = o;
    return;
  }
  __shared__ float tile[32][33];
  const float* src; __bf16* dst; int C, bx, by;
  bool is_wq;
  if (b < 3072) {
    int t = b - 2304; src = wq; dst = wqT; C = 1536;
    bx = (t % 48) * 32; by = (t / 48) * 32; is_wq = true;
  } else {
    int t = b - 3072; src = wo; dst = woT; C = 512;
    bx = (t & 15) * 32; by = (t >> 4) * 32; is_wq = false;
  }
  int tx = tid & 31, ty = tid >> 5;
#pragma unroll
  for (int i = 0; i < 32; i += 8)
    tile[ty + i][tx] = src[(by + ty + i) * C + bx + tx];
  __syncthreads();
#pragma unroll
  for (int i = 0; i < 32; i += 8) {
    int outrow = bx + ty + i;
    float v = tile[tx][ty + i];
    if (is_wq && outrow < 512) v *= 0.125f;  // fold q/sqrt(64)
    dst[outrow * 512 + by + tx] = (__bf16)v;
  }
}

// ---------------- bf16 MFMA GEMM, BK=32, dbuf global_load_lds ----------------
// (round-5 config — best measured). C[MxN] = A[MxK] * Bt[NxK]^T.
// Block tile BM x BN, 4 waves (2x2), wave tile (BM/2) x (BN/2).
// Fragment layouts (verified m89): A[m=lane&15][k=quad*8+j]; Bt[n=lane&15][k=quad*8+j];
// C/D: row=quad*4+reg, col=lane&15.
template <int BM, int BN>
__global__ __launch_bounds__(256) void gemm_kernel(
    const __bf16* __restrict__ A, const __bf16* __restrict__ Bt,
    void* __restrict__ C, int M, int N, int K, int c_is_f32) {
  constexpr int MT = BM / 32, NT = BN / 32, AR = BM / 4, BR = BN / 4;
  __shared__ __bf16 sA[2][BM * 32];
  __shared__ __bf16 sB[2][BN * 32];
  int tid = threadIdx.x;
  int wv = tid >> 6, lane = tid & 63;
  int quad = lane >> 4, r16 = lane & 15;
  int m0 = blockIdx.y * BM, n0 = blockIdx.x * BN;

  int rA = lane >> 2;           // 0..15
  int kc = (lane & 3) * 8;      // 0,8,16,24
  const __bf16* Ag0 = A + (long)(m0 + wv * AR + rA) * K + kc;
  const __bf16* Bg0 = Bt + (long)(n0 + wv * BR + rA) * K + kc;

  int mw = (wv & 1) * (BM / 2), nw = (wv >> 1) * (BN / 2);

  f32x4 acc[MT][NT];
#pragma unroll
  for (int mt = 0; mt < MT; ++mt)
#pragma unroll
    for (int nt = 0; nt < NT; ++nt) acc[mt][nt] = f32x4{0.f, 0.f, 0.f, 0.f};

  auto stage = [&](int buf, int k0) {
    gload_lds16(Ag0 + k0, &sA[buf][(wv * AR) * 32]);
    if (AR == 32)
      gload_lds16(Ag0 + (long)16 * K + k0, &sA[buf][(wv * AR + 16) * 32]);
    gload_lds16(Bg0 + k0, &sB[buf][(wv * BR) * 32]);
    if (BR == 32)
      gload_lds16(Bg0 + (long)16 * K + k0, &sB[buf][(wv * BR + 16) * 32]);
  };

  stage(0, 0);
  int cur = 0;
  for (int k0 = 0; k0 < K; k0 += 32) {
    __syncthreads();
    if (k0 + 32 < K) stage(cur ^ 1, k0 + 32);
    bf16x8 af[MT], bfr[NT];
#pragma unroll
    for (int mt = 0; mt < MT; ++mt)
      af[mt] = *(const bf16x8*)&sA[cur][(mw + mt * 16 + r16) * 32 + quad * 8];
#pragma unroll
    for (int nt = 0; nt < NT; ++nt)
      bfr[nt] = *(const bf16x8*)&sB[cur][(nw + nt * 16 + r16) * 32 + quad * 8];
#pragma unroll
    for (int mt = 0; mt < MT; ++mt)
#pragma unroll
      for (int nt = 0; nt < NT; ++nt)
        acc[mt][nt] = __builtin_amdgcn_mfma_f32_16x16x32_bf16(af[mt], bfr[nt], acc[mt][nt], 0, 0, 0);
    cur ^= 1;
  }

  __bf16* Cb = (__bf16*)C;
  float* Cf = (float*)C;
#pragma unroll
  for (int mt = 0; mt < MT; ++mt)
#pragma unroll
    for (int r = 0; r < 4; ++r) {
      int row = m0 + mw + mt * 16 + quad * 4 + r;
#pragma unroll
      for (int nt = 0; nt < NT; ++nt) {
        int col = n0 + nw + nt * 16 + r16;
        float v = acc[mt][nt][r];
        if (c_is_f32) Cf[(long)row * N + col] = v;
        else          Cb[(long)row * N + col] = (__bf16)v;
      }
    }
}

// ------- neighborhood attention, split-phase LDS (28.2 KB), 512 threads -------
// Block = 8x8 query tile x 1 head, 8 waves. ONE 196x72 bf16 buffer (28.2 KB):
// stage K -> logits in registers -> barrier -> overwrite with V (softmax in regs
// overlaps the V staging latency) -> barrier -> PV. 4 blocks/CU x 8 waves = 32
// waves/CU (100% occupancy) vs 2 blocks (16 waves) for the dual-buffer version.
// 8 lanes per query, 8 channels each. q-scale pre-folded into w_qkv (prep).
__global__ __launch_bounds__(512) void natten_attn_kernel(
    const __bf16* __restrict__ qkv, __bf16* __restrict__ o) {
  __shared__ __bf16 sKV[196 * KSTR];   // 28224 B
  int tid = threadIdx.x;
  int bid = blockIdx.x;                 // 0..575
  int nB = bid / 288;
  int rem = bid - nB * 288;
  int head = rem / 36;
  int tile = rem - head * 36;
  int tr = tile / 6, tc = tile - tr * 6;
  int r0 = tr * 8, c0 = tc * 8;
  int loH = r0 - 3; loH = loH < 0 ? 0 : (loH > 41 ? 41 : loH);
  int loW = c0 - 3; loW = loW < 0 ? 0 : (loW > 41 ? 41 : loW);

  // per-row global base (reused for K then V staging)
  int rowi = tid >> 3, ch = tid & 7;    // 512 thr = 196..(pad to 512/8=64 rows/pass)
  // staging loop covers 196 rows x 8 chunks with 512 threads -> 4 passes (3.0625 used)
  long gbase[4]; int ldst[4]; int npass = 0;
  for (int j = tid; j < 196 * 8; j += 512) {
    int ri = j >> 3, cc8 = j & 7;
    int rr = ri / 14, cc = ri - rr * 14;
    int hh = loH + rr; hh = hh > 47 ? 47 : hh;
    int wp = loW + cc; wp = wp > 47 ? 47 : wp;
    gbase[npass] = (long)(nB * 2304 + hh * 48 + wp) * QKV_N + head * 64 + cc8 * 8;
    ldst[npass] = ri * KSTR + cc8 * 8;
    ++npass;
  }

  // ---- stage K ----
  for (int p = 0; p < npass; ++p)
    *(uint4*)&sKV[ldst[p]] = *(const uint4*)&qkv[gbase[p] + 512];
  __syncthreads();

  int q = tid >> 3, s = tid & 7;        // 64 queries x 8 channel-slices
  int qr = q >> 3, qc = q & 7;
  int h = r0 + qr, w = c0 + qc;
  int pix = nB * 2304 + h * 48 + w;
  int hs = h - 3; hs = hs < 0 ? 0 : (hs > 41 ? 41 : hs); hs -= loH;
  int ws = w - 3; ws = ws < 0 ? 0 : (ws > 41 ? 41 : ws); ws -= loW;
  int base = (hs * 14 + ws) * KSTR + s * 8;

  bf16x8 q0 = *(const bf16x8*)&qkv[(long)pix * QKV_N + head * 64 + s * 8];
  float qf[8];
#pragma unroll
  for (int t = 0; t < 8; ++t) qf[t] = (float)q0[t];

  // ---- phase 1: 49 logits (8-ch partial + 3-step shuffle reduce over 8 lanes) ----
  float lg[49];
#pragma unroll
  for (int j = 0; j < 49; ++j) {
    int a = j / 7, b = j % 7;
    bf16x8 k0 = *(const bf16x8*)&sKV[base + (a * 14 + b) * KSTR];
    float acc = 0.f;
#pragma unroll
    for (int t = 0; t < 8; ++t) acc = fmaf(qf[t], (float)k0[t], acc);
    acc += __shfl_xor(acc, 1);
    acc += __shfl_xor(acc, 2);
    acc += __shfl_xor(acc, 4);
    lg[j] = acc;
  }
  __syncthreads();   // all K reads done; safe to overwrite buffer

  // ---- stage V (stores in flight while softmax runs below) ----
  for (int p = 0; p < npass; ++p)
    *(uint4*)&sKV[ldst[p]] = *(const uint4*)&qkv[gbase[p] + 1024];

  // softmax in registers (replicated across the 8 lanes of a query)
  float mx = lg[0];
#pragma unroll
  for (int j = 1; j < 49; ++j) mx = fmaxf(mx, lg[j]);
  float sm = 0.f;
#pragma unroll
  for (int j = 0; j < 49; ++j) { lg[j] = __expf(lg[j] - mx); sm += lg[j]; }
  float inv = 1.f / sm;
  __syncthreads();

  // ---- phase 2: PV, 8 channels per lane ----
  float ov[8];
#pragma unroll
  for (int t = 0; t < 8; ++t) ov[t] = 0.f;
#pragma unroll
  for (int j = 0; j < 49; ++j) {
    int a = j / 7, b = j % 7;
    float pj = lg[j] * inv;
    bf16x8 v0 = *(const bf16x8*)&sKV[base + (a * 14 + b) * KSTR];
#pragma unroll
    for (int t = 0; t < 8; ++t) ov[t] = fmaf(pj, (float)v0[t], ov[t]);
  }

  bf16x8 o0;
#pragma unroll
  for (int t = 0; t < 8; ++t) o0[t] = (__bf16)ov[t];
  *(bf16x8*)&o[(long)pix * D_MODEL + head * 64 + s * 8] = o0;
}

// ---------------- launch ----------------

extern "C" void kernel_launch(void* const* d_in, const int* in_sizes, int n_in,
                              void* d_out, int out_size, void* d_ws, size_t ws_size,
                              hipStream_t stream) {
  const float* x = (const float*)d_in[0];      // (2,48,48,512)
  const float* w_qkv = (const float*)d_in[1];  // (512,1536)
  const float* w_out = (const float*)d_in[2];  // (512,512)
  float* out = (float*)d_out;                  // (2,48,48,512)

  __bf16* ws = (__bf16*)d_ws;
  __bf16* xbf   = ws;                                   // 4608*512
  __bf16* wqkvT = xbf + N_PIX * D_MODEL;                // 1536*512
  __bf16* woutT = wqkvT + QKV_N * D_MODEL;              // 512*512
  __bf16* qkvb  = woutT + D_MODEL * D_MODEL;            // 4608*1536
  __bf16* obf   = qkvb + N_PIX * QKV_N;                 // 4608*512

  // prep: x->bf16 (2304 blocks) + w_qkv^T scaled (768) + w_out^T (256)
  prep_kernel<<<3328, 256, 0, stream>>>(x, w_qkv, w_out, xbf, wqkvT, woutT);
  // qkv = xbf @ w_qkv -> bf16 (4608 x 1536); 64x128 tile -> 864 blocks
  gemm_kernel<64, 128><<<dim3(QKV_N / 128, N_PIX / 64), 256, 0, stream>>>(
      xbf, wqkvT, qkvb, N_PIX, QKV_N, D_MODEL, 0);
  // attention -> obf (4608 x 512); split-phase LDS, 100% occupancy
  natten_attn_kernel<<<576, 512, 0, stream>>>(qkvb, obf);
  // out = obf @ w_out -> fp32; 64x64 tile -> 576 blocks
  gemm_kernel<64, 64><<<dim3(D_MODEL / 64, N_PIX / 64), 256, 0, stream>>>(
      obf, woutT, out, N_PIX, D_MODEL, D_MODEL, 1);
}